// Round 1
// baseline (1506.171 us; speedup 1.0000x reference)
//
#include <hip/hip_runtime.h>
#include <math.h>

// Shapes (fixed for this problem)
#define BB 2
#define HH 16
#define SS 2048
#define DD 1024
#define DK 64
#define BHS (BB*HH*SS)          // 65536 rows of x
#define INV_SCALE 0.03125f      // 1/sqrt(1024)

// ---------------------------------------------------------------------------
// Kernel 1: QKV projection.
// Treat x as [BHS, D] row-major; q/k/v outputs [BHS, DK] (same row flattening:
// (b*H+h)*S+s). Block computes 64 rows x 192 cols (q|k|v stacked), BK=32.
// ---------------------------------------------------------------------------
__global__ __launch_bounds__(256) void qkv_proj(
    const float* __restrict__ x,
    const float* __restrict__ wq, const float* __restrict__ wk,
    const float* __restrict__ wv,
    float* __restrict__ q, float* __restrict__ k, float* __restrict__ v)
{
    __shared__ float xs[64][33];    // +1 pad: row reads stride 33 -> distinct banks
    __shared__ float ws[192][33];
    const int tid = threadIdx.x;
    const int tx = tid & 15;        // 0..15 -> 12 cols each
    const int ty = tid >> 4;        // 0..15 -> 4 rows each
    const int rowbase = blockIdx.x * 64;

    float acc[4][12];
#pragma unroll
    for (int i = 0; i < 4; ++i)
#pragma unroll
        for (int j = 0; j < 12; ++j) acc[i][j] = 0.0f;

    for (int k0 = 0; k0 < DD; k0 += 32) {
        // load x tile 64x32 (512 float4, 2/thread)
#pragma unroll
        for (int it = 0; it < 2; ++it) {
            int li = tid + it * 256;          // 0..511
            int r  = li >> 3;                 // 8 float4 per row
            int c4 = li & 7;
            float4 t4 = *(const float4*)(x + (size_t)(rowbase + r) * DD + k0 + c4 * 4);
            xs[r][c4*4+0] = t4.x; xs[r][c4*4+1] = t4.y;
            xs[r][c4*4+2] = t4.z; xs[r][c4*4+3] = t4.w;
        }
        // load w tile 192x32 (1536 float4, 6/thread); rows 0-63 wq, 64-127 wk, 128-191 wv
#pragma unroll
        for (int it = 0; it < 6; ++it) {
            int li = tid + it * 256;          // 0..1535
            int r  = li >> 3;                 // 0..191
            int c4 = li & 7;
            const float* wsrc = (r < 64) ? wq : ((r < 128) ? wk : wv);
            int wr = r & 63;
            float4 t4 = *(const float4*)(wsrc + (size_t)wr * DD + k0 + c4 * 4);
            ws[r][c4*4+0] = t4.x; ws[r][c4*4+1] = t4.y;
            ws[r][c4*4+2] = t4.z; ws[r][c4*4+3] = t4.w;
        }
        __syncthreads();
#pragma unroll
        for (int kk = 0; kk < 32; ++kk) {
            float a[4], b[12];
#pragma unroll
            for (int i = 0; i < 4; ++i) a[i] = xs[ty*4+i][kk];
#pragma unroll
            for (int j = 0; j < 12; ++j) b[j] = ws[tx*12+j][kk];
#pragma unroll
            for (int i = 0; i < 4; ++i)
#pragma unroll
                for (int j = 0; j < 12; ++j) acc[i][j] += a[i] * b[j];
        }
        __syncthreads();
    }

#pragma unroll
    for (int i = 0; i < 4; ++i) {
        size_t m = (size_t)(rowbase + ty*4 + i);
#pragma unroll
        for (int j = 0; j < 12; ++j) {
            int c = tx*12 + j;
            float val = acc[i][j];
            if (c < 64)       q[m*DK + c]         = val;
            else if (c < 128) k[m*DK + (c - 64)]  = val;
            else              v[m*DK + (c - 128)] = val;
        }
    }
}

// ---------------------------------------------------------------------------
// Kernel 2: flash attention (online softmax), fp32.
// grid = (S/64 q-tiles, B*H). Block 256 threads: 64x64 score tile, each
// thread a 4x4 micro-tile (rows ty*4+i, cols tx*4+j).
// Ks and Ps share one LDS buffer (Ks dead after score compute).
// Output written directly in [B, S, H*DK] layout for the final GEMM.
// ---------------------------------------------------------------------------
__global__ __launch_bounds__(256) void flash_attn(
    const float* __restrict__ q, const float* __restrict__ k,
    const float* __restrict__ v, float* __restrict__ o)
{
    __shared__ float Qs[64][65];
    __shared__ float KP[64][65];   // K-tile, then P-tile
    __shared__ float Vs[64][64];   // unpadded: PV reads are 2-way (free), enables float4 ld/st
    const int tid = threadIdx.x;
    const int tx = tid & 15;
    const int ty = tid >> 4;
    const int qt = blockIdx.x;     // 0..31
    const int bh = blockIdx.y;     // 0..31
    const size_t hbase = (size_t)bh * SS * DK;

    // load Q tile (64x64; 1024 float4, 4/thread)
#pragma unroll
    for (int it = 0; it < 4; ++it) {
        int li = tid + it * 256;
        int r  = li >> 4;
        int c4 = li & 15;
        float4 t4 = *(const float4*)(q + hbase + (size_t)(qt*64 + r) * DK + c4 * 4);
        Qs[r][c4*4+0] = t4.x; Qs[r][c4*4+1] = t4.y;
        Qs[r][c4*4+2] = t4.z; Qs[r][c4*4+3] = t4.w;
    }

    float m_i[4], l_i[4], acc[4][4];
#pragma unroll
    for (int i = 0; i < 4; ++i) {
        m_i[i] = -INFINITY; l_i[i] = 0.0f;
#pragma unroll
        for (int j = 0; j < 4; ++j) acc[i][j] = 0.0f;
    }
    __syncthreads();

    for (int kt = 0; kt < 32; ++kt) {
        // load K,V tiles
#pragma unroll
        for (int it = 0; it < 4; ++it) {
            int li = tid + it * 256;
            int r  = li >> 4;
            int c4 = li & 15;
            float4 k4 = *(const float4*)(k + hbase + (size_t)(kt*64 + r) * DK + c4 * 4);
            KP[r][c4*4+0] = k4.x; KP[r][c4*4+1] = k4.y;
            KP[r][c4*4+2] = k4.z; KP[r][c4*4+3] = k4.w;
            float4 v4 = *(const float4*)(v + hbase + (size_t)(kt*64 + r) * DK + c4 * 4);
            *(float4*)&Vs[r][c4*4] = v4;
        }
        __syncthreads();

        // scores: 4x4 per thread, dot length 64
        float s[4][4];
#pragma unroll
        for (int i = 0; i < 4; ++i)
#pragma unroll
            for (int j = 0; j < 4; ++j) s[i][j] = 0.0f;
#pragma unroll 4
        for (int d = 0; d < 64; ++d) {
            float a[4], b[4];
#pragma unroll
            for (int i = 0; i < 4; ++i) a[i] = Qs[ty*4+i][d];
#pragma unroll
            for (int j = 0; j < 4; ++j) b[j] = KP[tx*4+j][d];
#pragma unroll
            for (int i = 0; i < 4; ++i)
#pragma unroll
                for (int j = 0; j < 4; ++j) s[i][j] += a[i] * b[j];
        }

        // online softmax update (per row; rows live across the 16-lane tx group)
        float alpha[4];
#pragma unroll
        for (int i = 0; i < 4; ++i) {
#pragma unroll
            for (int j = 0; j < 4; ++j) s[i][j] *= INV_SCALE;
            float rm = fmaxf(fmaxf(s[i][0], s[i][1]), fmaxf(s[i][2], s[i][3]));
#pragma unroll
            for (int off = 1; off < 16; off <<= 1)
                rm = fmaxf(rm, __shfl_xor(rm, off, 64));
            float mnew = fmaxf(m_i[i], rm);
            alpha[i] = __expf(m_i[i] - mnew);
            float rs = 0.0f;
#pragma unroll
            for (int j = 0; j < 4; ++j) { s[i][j] = __expf(s[i][j] - mnew); rs += s[i][j]; }
#pragma unroll
            for (int off = 1; off < 16; off <<= 1)
                rs += __shfl_xor(rs, off, 64);
            l_i[i] = l_i[i] * alpha[i] + rs;
            m_i[i] = mnew;
        }

        __syncthreads();   // everyone done reading KP as K-tile
#pragma unroll
        for (int i = 0; i < 4; ++i)
#pragma unroll
            for (int j = 0; j < 4; ++j) KP[ty*4+i][tx*4+j] = s[i][j];
        __syncthreads();   // P visible

        // O = O*alpha + P @ V
#pragma unroll
        for (int i = 0; i < 4; ++i)
#pragma unroll
            for (int j = 0; j < 4; ++j) acc[i][j] *= alpha[i];
#pragma unroll 2
        for (int t = 0; t < 64; ++t) {
            float4 vv = *(const float4*)&Vs[t][tx*4];
#pragma unroll
            for (int i = 0; i < 4; ++i) {
                float pv = KP[ty*4+i][t];
                acc[i][0] += pv * vv.x; acc[i][1] += pv * vv.y;
                acc[i][2] += pv * vv.z; acc[i][3] += pv * vv.w;
            }
        }
        __syncthreads();   // done with KP/Vs before next iteration's loads
    }

    // epilogue -> o[B, S, H*DK]
    const int b = bh >> 4, h = bh & 15;
#pragma unroll
    for (int i = 0; i < 4; ++i) {
        int srow = qt*64 + ty*4 + i;
        float rl = 1.0f / l_i[i];
        float4 o4 = { acc[i][0]*rl, acc[i][1]*rl, acc[i][2]*rl, acc[i][3]*rl };
        *(float4*)(o + ((size_t)(b*SS + srow) * (HH*DK)) + h*64 + tx*4) = o4;
    }
}

// ---------------------------------------------------------------------------
// Kernel 3: output projection. C[4096,1024] = A[4096,1024] @ wo^T.
// BM=BN=BK=64, block 256 threads, 4x4 micro-tile per thread.
// ---------------------------------------------------------------------------
__global__ __launch_bounds__(256) void out_proj(
    const float* __restrict__ a, const float* __restrict__ wo,
    float* __restrict__ c)
{
    __shared__ float As[64][65];
    __shared__ float Ws[64][65];
    const int tid = threadIdx.x;
    const int tx = tid & 15;
    const int ty = tid >> 4;
    const int mt = blockIdx.y;     // 0..63
    const int nt = blockIdx.x;     // 0..15

    float acc[4][4];
#pragma unroll
    for (int i = 0; i < 4; ++i)
#pragma unroll
        for (int j = 0; j < 4; ++j) acc[i][j] = 0.0f;

    for (int k0 = 0; k0 < DD; k0 += 64) {
#pragma unroll
        for (int it = 0; it < 4; ++it) {
            int li = tid + it * 256;
            int r  = li >> 4;
            int c4 = li & 15;
            float4 a4 = *(const float4*)(a + (size_t)(mt*64 + r) * DD + k0 + c4 * 4);
            As[r][c4*4+0] = a4.x; As[r][c4*4+1] = a4.y;
            As[r][c4*4+2] = a4.z; As[r][c4*4+3] = a4.w;
            float4 w4 = *(const float4*)(wo + (size_t)(nt*64 + r) * DD + k0 + c4 * 4);
            Ws[r][c4*4+0] = w4.x; Ws[r][c4*4+1] = w4.y;
            Ws[r][c4*4+2] = w4.z; Ws[r][c4*4+3] = w4.w;
        }
        __syncthreads();
#pragma unroll
        for (int kk = 0; kk < 64; ++kk) {
            float av[4], bv[4];
#pragma unroll
            for (int i = 0; i < 4; ++i) av[i] = As[ty*4+i][kk];
#pragma unroll
            for (int j = 0; j < 4; ++j) bv[j] = Ws[tx*4+j][kk];
#pragma unroll
            for (int i = 0; i < 4; ++i)
#pragma unroll
                for (int j = 0; j < 4; ++j) acc[i][j] += av[i] * bv[j];
        }
        __syncthreads();
    }

#pragma unroll
    for (int i = 0; i < 4; ++i) {
        float4 o4 = { acc[i][0], acc[i][1], acc[i][2], acc[i][3] };
        *(float4*)(c + (size_t)(mt*64 + ty*4 + i) * DD + nt*64 + tx*4) = o4;
    }
}

// ---------------------------------------------------------------------------
extern "C" void kernel_launch(void* const* d_in, const int* in_sizes, int n_in,
                              void* d_out, int out_size, void* d_ws, size_t ws_size,
                              hipStream_t stream) {
    const float* x  = (const float*)d_in[0];
    const float* wq = (const float*)d_in[1];
    const float* wk = (const float*)d_in[2];
    const float* wv = (const float*)d_in[3];
    const float* wo = (const float*)d_in[4];
    float* out = (float*)d_out;

    // workspace: q,k,v [B,H,S,DK] + attn_out [B,S,H*DK]  (4 x 16.8 MB = 67 MB)
    float* q  = (float*)d_ws;
    float* k  = q  + (size_t)BHS * DK;
    float* v  = k  + (size_t)BHS * DK;
    float* ao = v  + (size_t)BHS * DK;

    qkv_proj<<<dim3(BHS / 64), dim3(256), 0, stream>>>(x, wq, wk, wv, q, k, v);
    flash_attn<<<dim3(SS / 64, BB * HH), dim3(256), 0, stream>>>(q, k, v, ao);
    out_proj<<<dim3(DD / 64, (BB * SS) / 64), dim3(256), 0, stream>>>(ao, wo, out);
}

// Round 2
// 585.037 us; speedup vs baseline: 2.5745x; 2.5745x over previous
//
#include <hip/hip_runtime.h>
#include <math.h>

// Shapes (fixed)
#define BB 2
#define HH 16
#define SS 2048
#define DD 1024
#define DK 64
#define BHS (BB*HH*SS)          // 65536
#define INV_SCALE 0.03125f      // 1/sqrt(1024)

typedef short  bf16x8  __attribute__((ext_vector_type(8)));
typedef float  floatx4 __attribute__((ext_vector_type(4)));
typedef unsigned short u16;

#define MFMA(a,b,c) __builtin_amdgcn_mfma_f32_16x16x32_bf16((a),(b),(c),0,0,0)

__device__ __forceinline__ u16 f2bf(float f) {
    union { float f; unsigned u; } v; v.f = f;
    unsigned r = v.u + 0x7FFFu + ((v.u >> 16) & 1u);   // RNE
    return (u16)(r >> 16);
}
__device__ __forceinline__ bf16x8 ldfrag(const u16* p) {
    union { uint4 u; bf16x8 b; } c;
    c.u = *(const uint4*)p;
    return c.b;
}
__device__ __forceinline__ void stbf4(u16* p, float4 t) {  // 4xf32 -> 4xbf16, 8B store
    union { u16 s[4]; uint2 u; } c;
    c.s[0] = f2bf(t.x); c.s[1] = f2bf(t.y); c.s[2] = f2bf(t.z); c.s[3] = f2bf(t.w);
    *(uint2*)p = c.u;
}

// ---------------------------------------------------------------------------
// Kernel 1: QKV projection, bf16 MFMA.
// x [BHS,1024] fp32 -> q,k bf16 [BHS,64]; v written TRANSPOSED per head:
// vT[(bh*64+dk)*2048 + s] (bf16), via LDS transpose in the epilogue.
// Block: 256 thr (4 waves), BM=64 rows, N=192 (q|k|v), BK=64.
// ---------------------------------------------------------------------------
__global__ __launch_bounds__(256) void qkv_proj(
    const float* __restrict__ x,
    const float* __restrict__ wq, const float* __restrict__ wk,
    const float* __restrict__ wv,
    u16* __restrict__ q, u16* __restrict__ k, u16* __restrict__ vT)
{
    __shared__ __align__(16) u16 Xs[64][72];    // 9216 B (also reused as Vbuf)
    __shared__ __align__(16) u16 Ws[192][72];   // 27648 B
    const int tid  = threadIdx.x;
    const int w    = tid >> 6;
    const int lane = tid & 63;
    const int quad = lane >> 4;
    const int l16  = lane & 15;
    const int rowbase = blockIdx.x * 64;

    floatx4 acc[12];
#pragma unroll
    for (int n = 0; n < 12; ++n) acc[n] = (floatx4){0.f,0.f,0.f,0.f};

    for (int k0 = 0; k0 < DD; k0 += 64) {
        // stage X tile 64x64 fp32->bf16 (1024 float4 chunks, 4/thread)
#pragma unroll
        for (int it = 0; it < 4; ++it) {
            int li = tid + it * 256;
            int r  = li >> 4;
            int c4 = li & 15;
            float4 t = *(const float4*)(x + (size_t)(rowbase + r) * DD + k0 + c4 * 4);
            stbf4(&Xs[r][c4 * 4], t);
        }
        // stage W tile 192x64 (3072 chunks, 12/thread); rows 0-63 wq, 64-127 wk, 128-191 wv
#pragma unroll
        for (int it = 0; it < 12; ++it) {
            int li = tid + it * 256;
            int r  = li >> 4;
            int c4 = li & 15;
            const float* wsrc = (r < 64) ? wq : ((r < 128) ? wk : wv);
            float4 t = *(const float4*)(wsrc + (size_t)(r & 63) * DD + k0 + c4 * 4);
            stbf4(&Ws[r][c4 * 4], t);
        }
        __syncthreads();

        bf16x8 a0 = ldfrag(&Xs[w * 16 + l16][quad * 8]);
        bf16x8 a1 = ldfrag(&Xs[w * 16 + l16][32 + quad * 8]);
#pragma unroll
        for (int n = 0; n < 12; ++n) {
            bf16x8 b0 = ldfrag(&Ws[n * 16 + l16][quad * 8]);
            bf16x8 b1 = ldfrag(&Ws[n * 16 + l16][32 + quad * 8]);
            acc[n] = MFMA(a0, b0, acc[n]);
            acc[n] = MFMA(a1, b1, acc[n]);
        }
        __syncthreads();
    }

    // epilogue: D row = w*16 + quad*4 + reg (block-local), col = n*16 + l16
    // q: n 0..3, k: n 4..7 — direct bf16 stores (coalesced 32B per quad-group)
#pragma unroll
    for (int r = 0; r < 4; ++r) {
        int row = w * 16 + quad * 4 + r;
        size_t m = (size_t)(rowbase + row);
#pragma unroll
        for (int n = 0; n < 4; ++n)
            q[m * DK + n * 16 + l16] = f2bf(acc[n][r]);
#pragma unroll
        for (int n = 4; n < 8; ++n)
            k[m * DK + (n - 4) * 16 + l16] = f2bf(acc[n][r]);
    }
    // v: transpose through LDS (Xs dead after last barrier), write vT coalesced
    u16 (*Vbuf)[72] = Xs;
#pragma unroll
    for (int r = 0; r < 4; ++r) {
        int row = w * 16 + quad * 4 + r;
#pragma unroll
        for (int n = 8; n < 12; ++n)
            Vbuf[row][(n - 8) * 16 + l16] = f2bf(acc[n][r]);
    }
    __syncthreads();
    {
        const int dk = tid >> 2;            // 0..63
        const int sc = (tid & 3) * 16;      // s-chunk
        const int bh = rowbase >> 11;       // rowbase / 2048
        const int s0 = rowbase & 2047;
        union { u16 s[16]; uint4 u[2]; } t;
#pragma unroll
        for (int u = 0; u < 16; ++u) t.s[u] = Vbuf[sc + u][dk];
        uint4* dst = (uint4*)(vT + ((size_t)(bh * DK + dk)) * SS + s0 + sc);
        dst[0] = t.u[0];
        dst[1] = t.u[1];
    }
}

// ---------------------------------------------------------------------------
// Kernel 2: flash attention, bf16 MFMA, online softmax.
// grid (32 q-tiles, 32 bh). Block 256 thr = 4 waves; wave w owns q-rows
// w*16..w*16+15 of the 64-row tile. Per kt-tile (64 keys): QK^T (8 MFMA/wave),
// softmax in C-layout regs, P->LDS (per-wave), PV (8 MFMA/wave).
// Output written bf16 to ao[B,S,H*64].
// ---------------------------------------------------------------------------
__global__ __launch_bounds__(256) void flash_attn(
    const u16* __restrict__ q, const u16* __restrict__ k,
    const u16* __restrict__ vT, u16* __restrict__ ao)
{
    __shared__ __align__(16) u16 Qs[64][72];
    __shared__ __align__(16) u16 Ks[64][72];
    __shared__ __align__(16) u16 Vt[64][72];       // Vt[dk][t]
    __shared__ __align__(16) u16 Ps[4][16][72];    // per-wave P tile
    const int tid  = threadIdx.x;
    const int w    = tid >> 6;
    const int lane = tid & 63;
    const int quad = lane >> 4;
    const int l16  = lane & 15;
    const int qt   = blockIdx.x;
    const int bh   = blockIdx.y;
    const size_t kbase = (size_t)bh * SS * DK;     // q,k layout [bh*S + t][64]
    const size_t vbase = (size_t)bh * DK * SS;     // vT layout [bh*64 + dk][S]

    // load Q tile once (512 uint4 chunks, 2/thread)
#pragma unroll
    for (int it = 0; it < 2; ++it) {
        int li = tid + it * 256;
        int r  = li >> 3;
        int c8 = li & 7;
        *(uint4*)&Qs[r][c8 * 8] =
            *(const uint4*)(q + kbase + (size_t)(qt * 64 + r) * DK + c8 * 8);
    }

    float m_i[4], l_i[4];
    floatx4 acc_o[4];
#pragma unroll
    for (int r = 0; r < 4; ++r) { m_i[r] = -INFINITY; l_i[r] = 0.f; }
#pragma unroll
    for (int n = 0; n < 4; ++n) acc_o[n] = (floatx4){0.f,0.f,0.f,0.f};
    __syncthreads();

    for (int kt = 0; kt < SS / 64; ++kt) {
        // stage K tile [64 t][64 dk] and Vt tile [64 dk][64 t]
#pragma unroll
        for (int it = 0; it < 2; ++it) {
            int li = tid + it * 256;
            int r  = li >> 3;
            int c8 = li & 7;
            *(uint4*)&Ks[r][c8 * 8] =
                *(const uint4*)(k + kbase + (size_t)(kt * 64 + r) * DK + c8 * 8);
            *(uint4*)&Vt[r][c8 * 8] =
                *(const uint4*)(vT + vbase + (size_t)r * SS + kt * 64 + c8 * 8);
        }
        __syncthreads();

        // scores: wave rows w*16.., cols kt*64.. ; 4 n-tiles x 2 k-chunks
        floatx4 sc[4];
        {
            bf16x8 a0 = ldfrag(&Qs[w * 16 + l16][quad * 8]);
            bf16x8 a1 = ldfrag(&Qs[w * 16 + l16][32 + quad * 8]);
#pragma unroll
            for (int n = 0; n < 4; ++n) {
                sc[n] = (floatx4){0.f,0.f,0.f,0.f};
                bf16x8 b0 = ldfrag(&Ks[n * 16 + l16][quad * 8]);
                bf16x8 b1 = ldfrag(&Ks[n * 16 + l16][32 + quad * 8]);
                sc[n] = MFMA(a0, b0, sc[n]);
                sc[n] = MFMA(a1, b1, sc[n]);
            }
        }

        // online softmax per row r (row = quad*4+r); 16-lane reduce within quad
        float alpha[4];
#pragma unroll
        for (int r = 0; r < 4; ++r) {
            float s0 = sc[0][r] * INV_SCALE, s1 = sc[1][r] * INV_SCALE;
            float s2 = sc[2][r] * INV_SCALE, s3 = sc[3][r] * INV_SCALE;
            float rm = fmaxf(fmaxf(s0, s1), fmaxf(s2, s3));
#pragma unroll
            for (int off = 1; off < 16; off <<= 1)
                rm = fmaxf(rm, __shfl_xor(rm, off, 64));
            float mnew = fmaxf(m_i[r], rm);
            alpha[r] = __expf(m_i[r] - mnew);
            float p0 = __expf(s0 - mnew), p1 = __expf(s1 - mnew);
            float p2 = __expf(s2 - mnew), p3 = __expf(s3 - mnew);
            float rs = (p0 + p1) + (p2 + p3);
#pragma unroll
            for (int off = 1; off < 16; off <<= 1)
                rs += __shfl_xor(rs, off, 64);
            l_i[r] = l_i[r] * alpha[r] + rs;
            m_i[r] = mnew;
            // P back into sc[n][r] for the LDS write
            sc[0][r] = p0; sc[1][r] = p1; sc[2][r] = p2; sc[3][r] = p3;
        }

        // rescale O, write P (C-layout -> LDS -> A-layout)
#pragma unroll
        for (int n = 0; n < 4; ++n) {
#pragma unroll
            for (int r = 0; r < 4; ++r) acc_o[n][r] *= alpha[r];
#pragma unroll
            for (int r = 0; r < 4; ++r)
                Ps[w][quad * 4 + r][n * 16 + l16] = f2bf(sc[n][r]);
        }
        // Ps is per-wave private: no barrier needed (compiler inserts lgkmcnt)

        // PV: O += P[16 x 64t] * V[64t x 64dk]
#pragma unroll
        for (int kc = 0; kc < 2; ++kc) {
            bf16x8 a = ldfrag(&Ps[w][l16][kc * 32 + quad * 8]);
#pragma unroll
            for (int n = 0; n < 4; ++n) {
                bf16x8 b = ldfrag(&Vt[n * 16 + l16][kc * 32 + quad * 8]);
                acc_o[n] = MFMA(a, b, acc_o[n]);
            }
        }
        __syncthreads();   // Ks/Vt consumed; safe to restage
    }

    // epilogue -> ao[B,S,H*64] bf16
    const int b = bh >> 4, h = bh & 15;
#pragma unroll
    for (int r = 0; r < 4; ++r) {
        int srow = qt * 64 + w * 16 + quad * 4 + r;
        float rl = 1.0f / l_i[r];
        size_t base = ((size_t)(b * SS + srow)) * (HH * DK) + h * 64;
#pragma unroll
        for (int n = 0; n < 4; ++n)
            ao[base + n * 16 + l16] = f2bf(acc_o[n][r] * rl);
    }
}

// ---------------------------------------------------------------------------
// Kernel 3: output projection, bf16 MFMA. out[4096,1024] = ao @ wo^T (fp32 out).
// Block 256 thr (4 waves), BM=64, BN=64, BK=64.
// ---------------------------------------------------------------------------
__global__ __launch_bounds__(256) void out_proj(
    const u16* __restrict__ ao, const float* __restrict__ wo,
    float* __restrict__ out)
{
    __shared__ __align__(16) u16 As[64][72];
    __shared__ __align__(16) u16 Bs[64][72];
    const int tid  = threadIdx.x;
    const int w    = tid >> 6;
    const int lane = tid & 63;
    const int quad = lane >> 4;
    const int l16  = lane & 15;
    const int mt = blockIdx.y;
    const int nt = blockIdx.x;

    floatx4 acc[4];
#pragma unroll
    for (int n = 0; n < 4; ++n) acc[n] = (floatx4){0.f,0.f,0.f,0.f};

    for (int k0 = 0; k0 < DD; k0 += 64) {
        // A tile: bf16 copy (512 chunks, 2/thread)
#pragma unroll
        for (int it = 0; it < 2; ++it) {
            int li = tid + it * 256;
            int r  = li >> 3;
            int c8 = li & 7;
            *(uint4*)&As[r][c8 * 8] =
                *(const uint4*)(ao + (size_t)(mt * 64 + r) * DD + k0 + c8 * 8);
        }
        // B tile: wo rows nt*64.., fp32->bf16 (1024 chunks, 4/thread)
#pragma unroll
        for (int it = 0; it < 4; ++it) {
            int li = tid + it * 256;
            int r  = li >> 4;
            int c4 = li & 15;
            float4 t = *(const float4*)(wo + (size_t)(nt * 64 + r) * DD + k0 + c4 * 4);
            stbf4(&Bs[r][c4 * 4], t);
        }
        __syncthreads();

        bf16x8 a0 = ldfrag(&As[w * 16 + l16][quad * 8]);
        bf16x8 a1 = ldfrag(&As[w * 16 + l16][32 + quad * 8]);
#pragma unroll
        for (int n = 0; n < 4; ++n) {
            bf16x8 b0 = ldfrag(&Bs[n * 16 + l16][quad * 8]);
            bf16x8 b1 = ldfrag(&Bs[n * 16 + l16][32 + quad * 8]);
            acc[n] = MFMA(a0, b0, acc[n]);
            acc[n] = MFMA(a1, b1, acc[n]);
        }
        __syncthreads();
    }

#pragma unroll
    for (int r = 0; r < 4; ++r) {
        int row = mt * 64 + w * 16 + quad * 4 + r;
#pragma unroll
        for (int n = 0; n < 4; ++n)
            out[(size_t)row * DD + nt * 64 + n * 16 + l16] = acc[n][r];
    }
}

// ---------------------------------------------------------------------------
extern "C" void kernel_launch(void* const* d_in, const int* in_sizes, int n_in,
                              void* d_out, int out_size, void* d_ws, size_t ws_size,
                              hipStream_t stream) {
    const float* x  = (const float*)d_in[0];
    const float* wq = (const float*)d_in[1];
    const float* wk = (const float*)d_in[2];
    const float* wv = (const float*)d_in[3];
    const float* wo = (const float*)d_in[4];
    float* out = (float*)d_out;

    // workspace (bf16): q,k [BHS,64]; vT [B,H,64,S]; ao [B,S,1024]  = 33.6 MB
    u16* q  = (u16*)d_ws;
    u16* k  = q  + (size_t)BHS * DK;
    u16* vT = k  + (size_t)BHS * DK;
    u16* ao = vT + (size_t)BHS * DK;

    qkv_proj<<<dim3(BHS / 64), dim3(256), 0, stream>>>(x, wq, wk, wv, q, k, vT);
    flash_attn<<<dim3(SS / 64, BB * HH), dim3(256), 0, stream>>>(q, k, vT, ao);
    out_proj<<<dim3(DD / 64, (BB * SS) / 64), dim3(256), 0, stream>>>(ao, wo, out);
}